// Round 4
// baseline (109.710 us; speedup 1.0000x reference)
//
#include <hip/hip_runtime.h>
#include <cstdint>
#include <cstddef>

// Mask R-CNN detection post-processing. R13 = R12 structure (3 kernels) with
// the rank kernel's O(R^2) compare de-redundified.
// R12 post-mortem: sweep-absorb via ticket was neutral (edge cost ~= sc1 cost);
// kept for fewer dispatches. R13 change: rank loop had 8 waves each reading
// ALL 512 u64 keys (2048 ds_read_b128/block ~ 24.6K cyc on the one LDS port).
// Now 2 waves x 4 elements/lane share one key stream: 512 reads (~6.1K cyc),
// VALU ~8.2K cyc/wave on separate SIMDs -> ~3x faster rank phase. Outputs
// bit-identical: extra elements' score/index recovered exactly from key bits.
//   1. rank_boxes (81 x 512):  u64-key stable rank + sorted boxes + validity
//                              (wave-reduce validity, 1 barrier; 2-wave rank)
//   2. bitmega   (648 x 256):  IoU bitmatrix (R10 verbatim) + agent-scope supT
//                              stores + per-class ticket; last block sweeps
//                              inline on wave 0 (R7 sweep verbatim).
//   3. finalize  (8 x 512):    per-row max/argmax + distributed top-100.
// Stable sorts via integer keys (softmax scores >= 0 => raw-bit monotone):
//   key = (~bits(s) << 32) | index; ascending == argsort(-s).
// Decision-exact IoU band: RN(inter/denom) > 0.5 <=> 2*inter > denom*(1+2^-24);
// outside denom*(1 +/- 2^-22) the compare decides; inside falls back to the
// reference expression (absmax 0.0 through R12).
// Avoided (measured regressions): cooperative grid.sync (R5 +100us),
// 648-block device fences (R8 +48us), single-CU finalize tail (R6 ~+25us),
// spin-gated merges (R9 +4us), 81-block full merge (R11 +14us).

#define R 512
#define K 81
#define IM_W_MAX 1332.0f   // IM_W - 1
#define IM_H_MAX 799.0f    // IM_H - 1
#define XFORM_CLIP_F 4.135166556742356f  // log(1000/16)
#define NMS_THRESH_F 0.5f
#define SCORE_THRESH_F 0.001f
#define MAX_PER_IMG 100
#define POST_NMS_TOPN 300

// Agent-scope (device-coherent, L2-bypassing) u64 access: cross-XCD safe
// within a single dispatch without any cache-writeback fence.
__device__ __forceinline__ void store_agent_u64(unsigned long long* p,
                                                unsigned long long v) {
    __hip_atomic_store(p, v, __ATOMIC_RELAXED, __HIP_MEMORY_SCOPE_AGENT);
}
__device__ __forceinline__ unsigned long long load_agent_u64(
        const unsigned long long* p) {
    return __hip_atomic_load(p, __ATOMIC_RELAXED, __HIP_MEMORY_SCOPE_AGENT);
}

// Box transform for (roi r, class k). Value-identical to R1-R12 (absmax 0.0).
__device__ __forceinline__ float4 transform_box(const float* __restrict__ rois,
                                                const float* __restrict__ deltas,
                                                int r, int k) {
    float4 roi = ((const float4*)rois)[r];
    float4 d4  = *(const float4*)(deltas + (size_t)r * (4 * K) + 4 * k);
    float w  = roi.z - roi.x + 1.0f;
    float h  = roi.w - roi.y + 1.0f;
    float cx = roi.x + 0.5f * w;
    float cy = roi.y + 0.5f * h;
    float dx = d4.x / 10.0f;                       // WX
    float dy = d4.y / 10.0f;                       // WY
    float dw = fminf(d4.z / 5.0f, XFORM_CLIP_F);   // WW
    float dh = fminf(d4.w / 5.0f, XFORM_CLIP_F);   // WH
    float pcx = dx * w + cx;
    float pcy = dy * h + cy;
    float pw  = expf(dw) * w;
    float ph  = expf(dh) * h;
    float4 b;
    b.x = fminf(fmaxf(pcx - 0.5f * pw, 0.0f), IM_W_MAX);
    b.y = fminf(fmaxf(pcy - 0.5f * ph, 0.0f), IM_H_MAX);
    b.z = fminf(fmaxf(pcx + 0.5f * pw - 1.0f, 0.0f), IM_W_MAX);
    b.w = fminf(fmaxf(pcy + 0.5f * ph - 1.0f, 0.0f), IM_H_MAX);
    return b;
}

// Bit-exact banded IoU compare (R9/R10 verbatim).
__device__ __forceinline__ bool iou_sup(float4 bi, float ai, float4 bj, float aj) {
    float xx1 = fmaxf(bi.x, bj.x);
    float yy1 = fmaxf(bi.y, bj.y);
    float xx2 = fminf(bi.z, bj.z);
    float yy2 = fminf(bi.w, bj.w);
    float iw = fmaxf(xx2 - xx1 + 1.0f, 0.0f);
    float ih = fmaxf(yy2 - yy1 + 1.0f, 0.0f);
    float inter = iw * ih;
    float denom = ai + aj - inter;         // >= 0 always (inter <= min area)
    float two_i = inter + inter;           // exact (x2)
    bool sup = two_i > denom * 1.0000002f;     // 1+2^-22: sure-true bound
    if (!sup && !(two_i < denom * 0.99999976f)) {  // rare band: exact IEEE
        sup = (inter / denom) > NMS_THRESH_F;      // ref expression
    }
    return sup;
}

// ---------------------------------------------------------------------------
// 1. Per-class u64-key stable rank + sorted boxes/scores + validity.
//    R13: wave-shfl validity reduction (1 barrier); rank by 2 waves x 4
//    elements/lane sharing one broadcast key stream (LDS instrs 2048 -> 512).
// ---------------------------------------------------------------------------
__global__ void __launch_bounds__(512)
rank_boxes_kernel(const float* __restrict__ rois,
                  const float* __restrict__ deltas,
                  const float* __restrict__ scores,
                  float4* __restrict__ sbox_g,     // [K][R] sorted boxes
                  int* __restrict__ order_g,       // [K][R] order[rank]=orig
                  float* __restrict__ ssc_g,       // [K][R] sorted scores
                  int* __restrict__ valid_g,       // [K]
                  int* __restrict__ done_k) {      // [K] ticket counters
    const int k = blockIdx.x, tid = threadIdx.x;
    __shared__ unsigned long long s_key[R];        // 4 KB
    __shared__ float s_red[8];                     // per-wave maxima

    const float sc = scores[tid * K + k];          // strided, L2-resident
    {
        unsigned int bits = __float_as_uint(sc);   // sc >= 0: bits monotone
        s_key[tid] = ((unsigned long long)(~bits) << 32) | (unsigned int)tid;
    }
    // Wave-level max reduce (fmax = selection: order-free, bit-exact).
    {
        float m = sc;
        #pragma unroll
        for (int off = 32; off > 0; off >>= 1)
            m = fmaxf(m, __shfl_xor(m, off, 64));
        if ((tid & 63) == 0) s_red[tid >> 6] = m;
    }
    __syncthreads();                               // s_key + s_red ready
    float m8 = fmaxf(fmaxf(fmaxf(s_red[0], s_red[1]), fmaxf(s_red[2], s_red[3])),
                     fmaxf(fmaxf(s_red[4], s_red[5]), fmaxf(s_red[6], s_red[7])));
    const bool valid = (k != 0) && (m8 > SCORE_THRESH_F);        // uniform
    if (tid == 0) { valid_g[k] = valid; done_k[k] = 0; }         // ws poisoned
    if (!valid || tid >= 128) return;              // 2 waves rank 4 elems each

    const unsigned long long k0 = s_key[tid];
    const unsigned long long k1 = s_key[tid + 128];
    const unsigned long long k2 = s_key[tid + 256];
    const unsigned long long k3 = s_key[tid + 384];
    int c0 = 0, c1 = 0, c2 = 0, c3 = 0;            // exact stable ranks
    const ulonglong2* kp = (const ulonglong2*)s_key;  // uniform -> broadcast
    #pragma unroll 8
    for (int j2 = 0; j2 < R / 2; ++j2) {
        ulonglong2 kk = kp[j2];
        c0 += (kk.x < k0); c0 += (kk.y < k0);
        c1 += (kk.x < k1); c1 += (kk.y < k1);
        c2 += (kk.x < k2); c2 += (kk.y < k2);
        c3 += (kk.x < k3); c3 += (kk.y < k3);
    }
    // Scatter 4 elements; score/index recovered exactly from key bits.
    #pragma unroll
    for (int m = 0; m < 4; ++m) {
        const unsigned long long ke = (m == 0) ? k0 : (m == 1) ? k1
                                     : (m == 2) ? k2 : k3;
        const int cnt = (m == 0) ? c0 : (m == 1) ? c1 : (m == 2) ? c2 : c3;
        const int e   = (int)(unsigned int)(ke & 0xffffffffull);   // == tid+128m
        const float se = __uint_as_float(~(unsigned int)(ke >> 32));
        sbox_g[k * R + cnt]  = transform_box(rois, deltas, e, k);
        order_g[k * R + cnt] = e;
        ssc_g[k * R + cnt]   = se;
    }
}

// ---------------------------------------------------------------------------
// 2. bitmega: R10 bitmatrix (verbatim arithmetic) + per-class ticket + inline
//    sweep by the class's last-finishing block (wave 0). supT traffic is
//    agent-scope; everything rank produced is prior-dispatch (plain loads ok).
// ---------------------------------------------------------------------------
__global__ void __launch_bounds__(256)
bitmega_kernel(const float4* __restrict__ sbox_g,
               const int* __restrict__ valid_g,
               unsigned long long* __restrict__ supT_g,
               const int* __restrict__ order_g,
               const float* __restrict__ ssc_g,
               int* __restrict__ done_k,
               float* __restrict__ dists_t) {      // [K][R]
    const int b = blockIdx.x;
    const int k = b >> 3;
    const int w = b & 7;
    const int tid = threadIdx.x;

    __shared__ float4 s_jbox[64];  // 1 KB: the jj-window boxes
    __shared__ float  s_jarea[64]; // 256 B
    __shared__ int    s_closer;

    const bool valid = valid_g[k] != 0;            // block-uniform
    const int jbase = w * 64;

    if (valid) {
        if (tid < 64) {
            float4 bx = sbox_g[k * R + jbase + tid];
            s_jbox[tid]  = bx;
            s_jarea[tid] = (bx.z - bx.x + 1.0f) * (bx.w - bx.y + 1.0f);
        }
        const int i0 = tid;
        const float4 bi0 = sbox_g[k * R + i0];
        const float  ai0 = (bi0.z - bi0.x + 1.0f) * (bi0.w - bi0.y + 1.0f);

        if (w < 4) {
            __syncthreads();   // s_jbox ready
            // Rows i0+256 >= 256 > jbase+63 are never read by the sweep
            // (word w read-rows <= 64w+63 <= 255): no store needed.
            const int d0 = i0 - jbase;
            unsigned long long mask0 =
                (d0 < 0) ? ~0ull : ((d0 >= 63) ? 0ull : (~0ull << (d0 + 1)));
            unsigned long long bits0 = 0ull;
            if (mask0) {               // wave-uniform skip for fully-past waves
                #pragma unroll 8
                for (int jj = 0; jj < 64; ++jj) {
                    float4 bj = s_jbox[jj];    // broadcast LDS read
                    float  aj = s_jarea[jj];
                    bits0 |= (unsigned long long)iou_sup(bi0, ai0, bj, aj) << jj;
                }
            }
            store_agent_u64(&supT_g[k * 4096 + w * 512 + i0], bits0 & mask0);
        } else {
            const int i1 = i0 + 256;
            const float4 bi1 = sbox_g[k * R + i1];
            const float  ai1 = (bi1.z - bi1.x + 1.0f) * (bi1.w - bi1.y + 1.0f);
            __syncthreads();   // s_jbox ready
            // mask0 == ~0 for every lane (i0 <= 255 < jbase).
            const int d1 = i1 - jbase;
            unsigned long long mask1 =
                (d1 < 0) ? ~0ull : ((d1 >= 63) ? 0ull : (~0ull << (d1 + 1)));
            unsigned long long bits0 = 0ull, bits1 = 0ull;
            if (__ballot(mask1 != 0ull)) {     // wave-uniform: both rows live
                #pragma unroll 8
                for (int jj = 0; jj < 64; ++jj) {
                    float4 bj = s_jbox[jj];    // ONE broadcast load, TWO rows
                    float  aj = s_jarea[jj];
                    bits0 |= (unsigned long long)iou_sup(bi0, ai0, bj, aj) << jj;
                    bits1 |= (unsigned long long)iou_sup(bi1, ai1, bj, aj) << jj;
                }
            } else {                           // upper row fully past: i0 only
                #pragma unroll 8
                for (int jj = 0; jj < 64; ++jj) {
                    float4 bj = s_jbox[jj];
                    float  aj = s_jarea[jj];
                    bits0 |= (unsigned long long)iou_sup(bi0, ai0, bj, aj) << jj;
                }
            }
            store_agent_u64(&supT_g[k * 4096 + w * 512 + i0], bits0);
            store_agent_u64(&supT_g[k * 4096 + w * 512 + i1], bits1 & mask1);
        }
    } else {
        __syncthreads();       // match the valid path's barrier count
    }

    // Ticket: barrier above already forced each wave to drain vmcnt(0)
    // (compiler emits s_waitcnt vmcnt(0) before s_barrier), so every sc1
    // store of this block is globally visible. One relaxed device-scope add.
    __syncthreads();           // all waves' stores drained before the tick
    if (tid == 0) s_closer = (atomicAdd(&done_k[k], 1) == 7);
    __syncthreads();
    if (!s_closer) return;

    // ---- Closer: wave 0 runs this class's sweep (R7/R10 verbatim) ----
    if (tid >= 64) return;
    const int l = tid;         // lane 0..63

    if (!valid) {
        #pragma unroll
        for (int p = 0; p < 8; ++p) dists_t[k * R + p * 64 + l] = 0.0f;
        return;
    }

    // Prefetch scatter data (prior dispatch, plain loads; overlaps the sweep).
    int   ord[8];
    float ssc[8];
    #pragma unroll
    for (int p = 0; p < 8; ++p) {
        ord[p] = order_g[k * R + p * 64 + l];
        ssc[p] = ssc_g[k * R + p * 64 + l];
    }

    unsigned long long* base = supT_g + (size_t)k * 4096;
    unsigned long long rrow[8], rnext[8];
    #pragma unroll
    for (int w2 = 0; w2 < 8; ++w2)
        rrow[w2] = load_agent_u64(&base[w2 * 512 + l]);   // wb=0 rows

    unsigned long long kb[8];
    #pragma unroll
    for (int w2 = 0; w2 < 8; ++w2) kb[w2] = ~0ull;

    #pragma unroll
    for (int wb = 0; wb < 8; ++wb) {
        if (wb < 7) {                  // prefetch next wb's rows
            #pragma unroll
            for (int w2 = 0; w2 < 8; ++w2)
                rnext[w2] = (w2 > wb)
                    ? load_agent_u64(&base[w2 * 512 + (wb + 1) * 64 + l]) : 0ull;
        }

        // Intra-block greedy: zero-row lanes can't change state (exact skip).
        const unsigned long long nz = __ballot(rrow[wb] != 0ull);
        unsigned long long cur = kb[wb];
        unsigned long long m = cur & nz;
        while (m) {                    // wave-uniform serial sweep
            int bit = __builtin_ctzll(m);
            const unsigned int r_lo = (unsigned int)(rrow[wb] & 0xffffffffull);
            const unsigned int r_hi = (unsigned int)(rrow[wb] >> 32);
            unsigned long long row =
                ((unsigned long long)(unsigned int)__builtin_amdgcn_readlane((int)r_hi, bit) << 32) |
                 (unsigned long long)(unsigned int)__builtin_amdgcn_readlane((int)r_lo, bit);
            m &= m - 1;
            cur &= ~row;
            m   &= ~row;
        }
        kb[wb] = cur;

        // Inter-block pruning: OR of kept rows' future words (ballot-guarded).
        #pragma unroll
        for (int w2 = wb + 1; w2 < 8; ++w2) {
            unsigned long long contrib = ((cur >> l) & 1ull) ? rrow[w2] : 0ull;
            if (__ballot(contrib != 0ull)) {
                #pragma unroll
                for (int off = 32; off > 0; off >>= 1)
                    contrib |= __shfl_xor(contrib, off, 64);
                kb[w2] &= ~contrib;
            }
        }

        #pragma unroll
        for (int w2 = 0; w2 < 8; ++w2) rrow[w2] = rnext[w2];
    }

    // cumsum(keep) <= 300 cut, sorted-rank order (uniform, lane-redundant).
    int total = 0;
    #pragma unroll
    for (int w2 = 0; w2 < 8; ++w2) total += __popcll(kb[w2]);
    if (total > POST_NMS_TOPN) {
        int cnt = 0;
        #pragma unroll
        for (int w2 = 0; w2 < 8; ++w2) {
            int pc = __popcll(kb[w2]);
            if (cnt + pc <= POST_NMS_TOPN) { cnt += pc; continue; }
            unsigned long long word = kb[w2], outw = 0ull;
            int room = POST_NMS_TOPN - cnt;
            while (room > 0) {
                unsigned long long lsb = word & (~word + 1ull);
                outw |= lsb; word ^= lsb; --room;
            }
            kb[w2] = outw; cnt = POST_NMS_TOPN;
        }
    }

    // Scatter masked scores back to original index order (plain stores;
    // finalize is the next dispatch -> kernel-boundary coherence).
    #pragma unroll
    for (int p = 0; p < 8; ++p)
        dists_t[k * R + ord[p]] = ((kb[p] >> l) & 1ull) ? ssc[p] : 0.0f;
}

// ---------------------------------------------------------------------------
// 3. Finalize (R7-proven verbatim): 8 blocks; each computes scores_pre/argmax
//    for all 512 rois (coalesced, redundant), ranks its own 64 rois with
//    8 threads/roi + segmented shfl_xor sum. Exactly 100 winners write.
//    Output (700 floats): [0..499] out(100x5), [500..599] labels, [600..699] top.
// ---------------------------------------------------------------------------
__global__ void __launch_bounds__(512)
finalize_kernel(const float* __restrict__ dists_t,
                const float* __restrict__ rois,
                const float* __restrict__ deltas,
                float* __restrict__ out) {
    const int b = blockIdx.x;      // 0..7 -> rois [b*64, b*64+64)
    const int t = threadIdx.x;
    __shared__ unsigned long long s_key[R];   // 4 KB
    __shared__ int s_arg[R];                  // 2 KB

    // Phase A: per-roi max/first-argmax over K classes (coalesced reads).
    {
        const int r = t;
        float vmax = dists_t[r];   // kk = 0 column (always zeros)
        int arg = 0;
        #pragma unroll 8
        for (int kk = 1; kk < K; ++kk) {
            float v = dists_t[kk * R + r];
            if (v > vmax) { vmax = v; arg = kk; }   // first-occurrence argmax
        }
        unsigned int bits = __float_as_uint(vmax);  // vmax >= 0
        s_key[r] = ((unsigned long long)(~bits) << 32) | (unsigned int)r;
        s_arg[r] = arg;
    }
    __syncthreads();

    // Phase B: rank this block's 64 rois. 8 threads/roi, 64 keys each;
    // chunk-rotated index avoids bank conflicts; order-free sum.
    const int ri = b * 64 + (t >> 3);
    const int c  = t & 7;
    const unsigned long long ki = s_key[ri];
    int cnt = 0;
    #pragma unroll 8
    for (int j = 0; j < 64; ++j) {
        int jj = (j + c * 8) & 63;
        cnt += (s_key[c * 64 + jj] < ki);
    }
    cnt += __shfl_xor(cnt, 1, 64);     // sum within the 8-lane segment
    cnt += __shfl_xor(cnt, 2, 64);
    cnt += __shfl_xor(cnt, 4, 64);

    if (c == 0 && cnt < MAX_PER_IMG) { // exactly 100 winners grid-wide
        float vmax = __uint_as_float(~(unsigned int)(ki >> 32));
        int arg = s_arg[ri];
        bool valid = vmax > SCORE_THRESH_F;
        float4 bx = transform_box(rois, deltas, ri, arg);
        out[cnt * 5 + 0] = valid ? vmax : 0.0f;
        out[cnt * 5 + 1] = valid ? bx.x : 0.0f;
        out[cnt * 5 + 2] = valid ? bx.y : 0.0f;
        out[cnt * 5 + 3] = valid ? bx.z : 0.0f;
        out[cnt * 5 + 4] = valid ? bx.w : 0.0f;
        out[500 + cnt] = (float)arg;   // labels_all
        out[600 + cnt] = (float)ri;    // top
    }
}

// ---------------------------------------------------------------------------
extern "C" void kernel_launch(void* const* d_in, const int* in_sizes, int n_in,
                              void* d_out, int out_size, void* d_ws, size_t ws_size,
                              hipStream_t stream) {
    const float* rois   = (const float*)d_in[0];   // [512,4]
    const float* deltas = (const float*)d_in[1];   // [512,324]
    const float* scores = (const float*)d_in[2];   // [512,81]
    float* out = (float*)d_out;                    // 700 floats

    char* ws = (char*)d_ws;                        // ~3.82 MB used
    float4* sbox_g  = (float4*)(ws + 0);                              // 663,552 B
    int*    order_g = (int*)   (ws + 663552);                         // 165,888 B
    float*  ssc_g   = (float*) (ws + 829440);                         // 165,888 B
    int*    valid_g = (int*)   (ws + 995328);                         //     512 B
    float*  dists_t = (float*) (ws + 995840);                         // 165,888 B
    unsigned long long* supT_g = (unsigned long long*)(ws + 1161728); // 2,654,208 B
    int*    done_k  = (int*)   (ws + 3815936);                        //     324 B

    rank_boxes_kernel<<<K, 512, 0, stream>>>(rois, deltas, scores,
                                             sbox_g, order_g, ssc_g,
                                             valid_g, done_k);
    bitmega_kernel   <<<K * 8, 256, 0, stream>>>(sbox_g, valid_g, supT_g,
                                                 order_g, ssc_g, done_k, dists_t);
    finalize_kernel  <<<8, 512, 0, stream>>>(dists_t, rois, deltas, out);
}

// Round 5
// 105.469 us; speedup vs baseline: 1.0402x; 1.0402x over previous
//
#include <hip/hip_runtime.h>
#include <cstdint>
#include <cstddef>

// Mask R-CNN detection post-processing. R14 = R12 (best 3-kernel config,
// 106.4us, tied with R10's 105.98) with R13's rank split REVERTED.
// R13 post-mortem: 2-wave x 4-elem rank regressed +3.3us -- the 8-wave
// redundant broadcast rank was already TLP-hidden; narrowing to 128 threads
// exposed scattered transform/store latency. Reverted. Kept from R13 only the
// 1-barrier wave-shfl validity max-reduce (fmax = selection, bit-exact).
//   1. rank_boxes (81 x 512):  u64-key stable rank + sorted boxes + validity
//   2. bitmega   (648 x 256):  IoU bitmatrix (R10 verbatim) + agent-scope supT
//                              stores + per-class ticket; last block sweeps
//                              inline on wave 0 (R7 sweep verbatim).
//   3. finalize  (8 x 512):    per-row max/argmax + distributed top-100.
// Stable sorts via integer keys (softmax scores >= 0 => raw-bit monotone):
//   key = (~bits(s) << 32) | index; ascending == argsort(-s).
// Decision-exact IoU band: RN(inter/denom) > 0.5 <=> 2*inter > denom*(1+2^-24);
// outside denom*(1 +/- 2^-22) the compare decides; inside falls back to the
// reference expression (absmax 0.0 through R13).
// Measured-regression ledger: coop grid.sync (R5 +100us), 648-block device
// fences (R8 +48us), single-CU finalize tail (R6 ~+25us), spin-gated merges
// (R9 +4us), 81-block full merge (R11 +14us), 2-wave rank (R13 +3.3us).

#define R 512
#define K 81
#define IM_W_MAX 1332.0f   // IM_W - 1
#define IM_H_MAX 799.0f    // IM_H - 1
#define XFORM_CLIP_F 4.135166556742356f  // log(1000/16)
#define NMS_THRESH_F 0.5f
#define SCORE_THRESH_F 0.001f
#define MAX_PER_IMG 100
#define POST_NMS_TOPN 300

// Agent-scope (device-coherent, L2-bypassing) u64 access: cross-XCD safe
// within a single dispatch without any cache-writeback fence.
__device__ __forceinline__ void store_agent_u64(unsigned long long* p,
                                                unsigned long long v) {
    __hip_atomic_store(p, v, __ATOMIC_RELAXED, __HIP_MEMORY_SCOPE_AGENT);
}
__device__ __forceinline__ unsigned long long load_agent_u64(
        const unsigned long long* p) {
    return __hip_atomic_load(p, __ATOMIC_RELAXED, __HIP_MEMORY_SCOPE_AGENT);
}

// Box transform for (roi r, class k). Value-identical to R1-R13 (absmax 0.0).
__device__ __forceinline__ float4 transform_box(const float* __restrict__ rois,
                                                const float* __restrict__ deltas,
                                                int r, int k) {
    float4 roi = ((const float4*)rois)[r];
    float4 d4  = *(const float4*)(deltas + (size_t)r * (4 * K) + 4 * k);
    float w  = roi.z - roi.x + 1.0f;
    float h  = roi.w - roi.y + 1.0f;
    float cx = roi.x + 0.5f * w;
    float cy = roi.y + 0.5f * h;
    float dx = d4.x / 10.0f;                       // WX
    float dy = d4.y / 10.0f;                       // WY
    float dw = fminf(d4.z / 5.0f, XFORM_CLIP_F);   // WW
    float dh = fminf(d4.w / 5.0f, XFORM_CLIP_F);   // WH
    float pcx = dx * w + cx;
    float pcy = dy * h + cy;
    float pw  = expf(dw) * w;
    float ph  = expf(dh) * h;
    float4 b;
    b.x = fminf(fmaxf(pcx - 0.5f * pw, 0.0f), IM_W_MAX);
    b.y = fminf(fmaxf(pcy - 0.5f * ph, 0.0f), IM_H_MAX);
    b.z = fminf(fmaxf(pcx + 0.5f * pw - 1.0f, 0.0f), IM_W_MAX);
    b.w = fminf(fmaxf(pcy + 0.5f * ph - 1.0f, 0.0f), IM_H_MAX);
    return b;
}

// Bit-exact banded IoU compare (R9/R10 verbatim).
__device__ __forceinline__ bool iou_sup(float4 bi, float ai, float4 bj, float aj) {
    float xx1 = fmaxf(bi.x, bj.x);
    float yy1 = fmaxf(bi.y, bj.y);
    float xx2 = fminf(bi.z, bj.z);
    float yy2 = fminf(bi.w, bj.w);
    float iw = fmaxf(xx2 - xx1 + 1.0f, 0.0f);
    float ih = fmaxf(yy2 - yy1 + 1.0f, 0.0f);
    float inter = iw * ih;
    float denom = ai + aj - inter;         // >= 0 always (inter <= min area)
    float two_i = inter + inter;           // exact (x2)
    bool sup = two_i > denom * 1.0000002f;     // 1+2^-22: sure-true bound
    if (!sup && !(two_i < denom * 0.99999976f)) {  // rare band: exact IEEE
        sup = (inter / denom) > NMS_THRESH_F;      // ref expression
    }
    return sup;
}

// ---------------------------------------------------------------------------
// 1. Per-class u64-key stable rank + sorted boxes/scores + validity
//    (R6/R7/R12-proven 8-wave form) + done_k[k] = 0 for kernel 2's tickets.
//    Only change vs R12: 1-barrier wave-shfl max reduce (was 9-barrier tree).
// ---------------------------------------------------------------------------
__global__ void __launch_bounds__(512)
rank_boxes_kernel(const float* __restrict__ rois,
                  const float* __restrict__ deltas,
                  const float* __restrict__ scores,
                  float4* __restrict__ sbox_g,     // [K][R] sorted boxes
                  int* __restrict__ order_g,       // [K][R] order[rank]=orig
                  float* __restrict__ ssc_g,       // [K][R] sorted scores
                  int* __restrict__ valid_g,       // [K]
                  int* __restrict__ done_k) {      // [K] ticket counters
    const int k = blockIdx.x, tid = threadIdx.x;
    __shared__ unsigned long long s_key[R];        // 4 KB
    __shared__ float s_red[8];                     // per-wave maxima

    const float sc = scores[tid * K + k];          // strided, L2-resident
    {
        unsigned int bits = __float_as_uint(sc);   // sc >= 0: bits monotone
        s_key[tid] = ((unsigned long long)(~bits) << 32) | (unsigned int)tid;
    }
    // Wave-level max reduce (fmax = selection: order-free, bit-exact).
    {
        float m = sc;
        #pragma unroll
        for (int off = 32; off > 0; off >>= 1)
            m = fmaxf(m, __shfl_xor(m, off, 64));
        if ((tid & 63) == 0) s_red[tid >> 6] = m;
    }
    __syncthreads();                               // s_key + s_red ready
    float m8 = fmaxf(fmaxf(fmaxf(s_red[0], s_red[1]), fmaxf(s_red[2], s_red[3])),
                     fmaxf(fmaxf(s_red[4], s_red[5]), fmaxf(s_red[6], s_red[7])));
    const bool valid = (k != 0) && (m8 > SCORE_THRESH_F);        // uniform
    if (tid == 0) { valid_g[k] = valid; done_k[k] = 0; }         // ws poisoned
    if (!valid) return;

    const unsigned long long ki = s_key[tid];
    int cnt = 0;                                   // exact stable rank
    const ulonglong2* kp = (const ulonglong2*)s_key;  // uniform j2 -> broadcast
    #pragma unroll 8
    for (int j2 = 0; j2 < R / 2; ++j2) {
        ulonglong2 k2 = kp[j2];
        cnt += (k2.x < ki);
        cnt += (k2.y < ki);
    }
    sbox_g[k * R + cnt]  = transform_box(rois, deltas, tid, k);
    order_g[k * R + cnt] = tid;
    ssc_g[k * R + cnt]   = sc;
}

// ---------------------------------------------------------------------------
// 2. bitmega: R10 bitmatrix (verbatim arithmetic) + per-class ticket + inline
//    sweep by the class's last-finishing block (wave 0). supT traffic is
//    agent-scope; everything rank produced is prior-dispatch (plain loads ok).
// ---------------------------------------------------------------------------
__global__ void __launch_bounds__(256)
bitmega_kernel(const float4* __restrict__ sbox_g,
               const int* __restrict__ valid_g,
               unsigned long long* __restrict__ supT_g,
               const int* __restrict__ order_g,
               const float* __restrict__ ssc_g,
               int* __restrict__ done_k,
               float* __restrict__ dists_t) {      // [K][R]
    const int b = blockIdx.x;
    const int k = b >> 3;
    const int w = b & 7;
    const int tid = threadIdx.x;

    __shared__ float4 s_jbox[64];  // 1 KB: the jj-window boxes
    __shared__ float  s_jarea[64]; // 256 B
    __shared__ int    s_closer;

    const bool valid = valid_g[k] != 0;            // block-uniform
    const int jbase = w * 64;

    if (valid) {
        if (tid < 64) {
            float4 bx = sbox_g[k * R + jbase + tid];
            s_jbox[tid]  = bx;
            s_jarea[tid] = (bx.z - bx.x + 1.0f) * (bx.w - bx.y + 1.0f);
        }
        const int i0 = tid;
        const float4 bi0 = sbox_g[k * R + i0];
        const float  ai0 = (bi0.z - bi0.x + 1.0f) * (bi0.w - bi0.y + 1.0f);

        if (w < 4) {
            __syncthreads();   // s_jbox ready
            // Rows i0+256 >= 256 > jbase+63 are never read by the sweep
            // (word w read-rows <= 64w+63 <= 255): no store needed.
            const int d0 = i0 - jbase;
            unsigned long long mask0 =
                (d0 < 0) ? ~0ull : ((d0 >= 63) ? 0ull : (~0ull << (d0 + 1)));
            unsigned long long bits0 = 0ull;
            if (mask0) {               // wave-uniform skip for fully-past waves
                #pragma unroll 8
                for (int jj = 0; jj < 64; ++jj) {
                    float4 bj = s_jbox[jj];    // broadcast LDS read
                    float  aj = s_jarea[jj];
                    bits0 |= (unsigned long long)iou_sup(bi0, ai0, bj, aj) << jj;
                }
            }
            store_agent_u64(&supT_g[k * 4096 + w * 512 + i0], bits0 & mask0);
        } else {
            const int i1 = i0 + 256;
            const float4 bi1 = sbox_g[k * R + i1];
            const float  ai1 = (bi1.z - bi1.x + 1.0f) * (bi1.w - bi1.y + 1.0f);
            __syncthreads();   // s_jbox ready
            // mask0 == ~0 for every lane (i0 <= 255 < jbase).
            const int d1 = i1 - jbase;
            unsigned long long mask1 =
                (d1 < 0) ? ~0ull : ((d1 >= 63) ? 0ull : (~0ull << (d1 + 1)));
            unsigned long long bits0 = 0ull, bits1 = 0ull;
            if (__ballot(mask1 != 0ull)) {     // wave-uniform: both rows live
                #pragma unroll 8
                for (int jj = 0; jj < 64; ++jj) {
                    float4 bj = s_jbox[jj];    // ONE broadcast load, TWO rows
                    float  aj = s_jarea[jj];
                    bits0 |= (unsigned long long)iou_sup(bi0, ai0, bj, aj) << jj;
                    bits1 |= (unsigned long long)iou_sup(bi1, ai1, bj, aj) << jj;
                }
            } else {                           // upper row fully past: i0 only
                #pragma unroll 8
                for (int jj = 0; jj < 64; ++jj) {
                    float4 bj = s_jbox[jj];
                    float  aj = s_jarea[jj];
                    bits0 |= (unsigned long long)iou_sup(bi0, ai0, bj, aj) << jj;
                }
            }
            store_agent_u64(&supT_g[k * 4096 + w * 512 + i0], bits0);
            store_agent_u64(&supT_g[k * 4096 + w * 512 + i1], bits1 & mask1);
        }
    } else {
        __syncthreads();       // match the valid path's barrier count
    }

    // Ticket: barrier above already forced each wave to drain vmcnt(0)
    // (compiler emits s_waitcnt vmcnt(0) before s_barrier), so every sc1
    // store of this block is globally visible. One relaxed device-scope add.
    __syncthreads();           // all waves' stores drained before the tick
    if (tid == 0) s_closer = (atomicAdd(&done_k[k], 1) == 7);
    __syncthreads();
    if (!s_closer) return;

    // ---- Closer: wave 0 runs this class's sweep (R7/R10 verbatim) ----
    if (tid >= 64) return;
    const int l = tid;         // lane 0..63

    if (!valid) {
        #pragma unroll
        for (int p = 0; p < 8; ++p) dists_t[k * R + p * 64 + l] = 0.0f;
        return;
    }

    // Prefetch scatter data (prior dispatch, plain loads; overlaps the sweep).
    int   ord[8];
    float ssc[8];
    #pragma unroll
    for (int p = 0; p < 8; ++p) {
        ord[p] = order_g[k * R + p * 64 + l];
        ssc[p] = ssc_g[k * R + p * 64 + l];
    }

    unsigned long long* base = supT_g + (size_t)k * 4096;
    unsigned long long rrow[8], rnext[8];
    #pragma unroll
    for (int w2 = 0; w2 < 8; ++w2)
        rrow[w2] = load_agent_u64(&base[w2 * 512 + l]);   // wb=0 rows

    unsigned long long kb[8];
    #pragma unroll
    for (int w2 = 0; w2 < 8; ++w2) kb[w2] = ~0ull;

    #pragma unroll
    for (int wb = 0; wb < 8; ++wb) {
        if (wb < 7) {                  // prefetch next wb's rows
            #pragma unroll
            for (int w2 = 0; w2 < 8; ++w2)
                rnext[w2] = (w2 > wb)
                    ? load_agent_u64(&base[w2 * 512 + (wb + 1) * 64 + l]) : 0ull;
        }

        // Intra-block greedy: zero-row lanes can't change state (exact skip).
        const unsigned long long nz = __ballot(rrow[wb] != 0ull);
        unsigned long long cur = kb[wb];
        unsigned long long m = cur & nz;
        while (m) {                    // wave-uniform serial sweep
            int bit = __builtin_ctzll(m);
            const unsigned int r_lo = (unsigned int)(rrow[wb] & 0xffffffffull);
            const unsigned int r_hi = (unsigned int)(rrow[wb] >> 32);
            unsigned long long row =
                ((unsigned long long)(unsigned int)__builtin_amdgcn_readlane((int)r_hi, bit) << 32) |
                 (unsigned long long)(unsigned int)__builtin_amdgcn_readlane((int)r_lo, bit);
            m &= m - 1;
            cur &= ~row;
            m   &= ~row;
        }
        kb[wb] = cur;

        // Inter-block pruning: OR of kept rows' future words (ballot-guarded).
        #pragma unroll
        for (int w2 = wb + 1; w2 < 8; ++w2) {
            unsigned long long contrib = ((cur >> l) & 1ull) ? rrow[w2] : 0ull;
            if (__ballot(contrib != 0ull)) {
                #pragma unroll
                for (int off = 32; off > 0; off >>= 1)
                    contrib |= __shfl_xor(contrib, off, 64);
                kb[w2] &= ~contrib;
            }
        }

        #pragma unroll
        for (int w2 = 0; w2 < 8; ++w2) rrow[w2] = rnext[w2];
    }

    // cumsum(keep) <= 300 cut, sorted-rank order (uniform, lane-redundant).
    int total = 0;
    #pragma unroll
    for (int w2 = 0; w2 < 8; ++w2) total += __popcll(kb[w2]);
    if (total > POST_NMS_TOPN) {
        int cnt = 0;
        #pragma unroll
        for (int w2 = 0; w2 < 8; ++w2) {
            int pc = __popcll(kb[w2]);
            if (cnt + pc <= POST_NMS_TOPN) { cnt += pc; continue; }
            unsigned long long word = kb[w2], outw = 0ull;
            int room = POST_NMS_TOPN - cnt;
            while (room > 0) {
                unsigned long long lsb = word & (~word + 1ull);
                outw |= lsb; word ^= lsb; --room;
            }
            kb[w2] = outw; cnt = POST_NMS_TOPN;
        }
    }

    // Scatter masked scores back to original index order (plain stores;
    // finalize is the next dispatch -> kernel-boundary coherence).
    #pragma unroll
    for (int p = 0; p < 8; ++p)
        dists_t[k * R + ord[p]] = ((kb[p] >> l) & 1ull) ? ssc[p] : 0.0f;
}

// ---------------------------------------------------------------------------
// 3. Finalize (R7-proven verbatim): 8 blocks; each computes scores_pre/argmax
//    for all 512 rois (coalesced, redundant), ranks its own 64 rois with
//    8 threads/roi + segmented shfl_xor sum. Exactly 100 winners write.
//    Output (700 floats): [0..499] out(100x5), [500..599] labels, [600..699] top.
// ---------------------------------------------------------------------------
__global__ void __launch_bounds__(512)
finalize_kernel(const float* __restrict__ dists_t,
                const float* __restrict__ rois,
                const float* __restrict__ deltas,
                float* __restrict__ out) {
    const int b = blockIdx.x;      // 0..7 -> rois [b*64, b*64+64)
    const int t = threadIdx.x;
    __shared__ unsigned long long s_key[R];   // 4 KB
    __shared__ int s_arg[R];                  // 2 KB

    // Phase A: per-roi max/first-argmax over K classes (coalesced reads).
    {
        const int r = t;
        float vmax = dists_t[r];   // kk = 0 column (always zeros)
        int arg = 0;
        #pragma unroll 8
        for (int kk = 1; kk < K; ++kk) {
            float v = dists_t[kk * R + r];
            if (v > vmax) { vmax = v; arg = kk; }   // first-occurrence argmax
        }
        unsigned int bits = __float_as_uint(vmax);  // vmax >= 0
        s_key[r] = ((unsigned long long)(~bits) << 32) | (unsigned int)r;
        s_arg[r] = arg;
    }
    __syncthreads();

    // Phase B: rank this block's 64 rois. 8 threads/roi, 64 keys each;
    // chunk-rotated index avoids bank conflicts; order-free sum.
    const int ri = b * 64 + (t >> 3);
    const int c  = t & 7;
    const unsigned long long ki = s_key[ri];
    int cnt = 0;
    #pragma unroll 8
    for (int j = 0; j < 64; ++j) {
        int jj = (j + c * 8) & 63;
        cnt += (s_key[c * 64 + jj] < ki);
    }
    cnt += __shfl_xor(cnt, 1, 64);     // sum within the 8-lane segment
    cnt += __shfl_xor(cnt, 2, 64);
    cnt += __shfl_xor(cnt, 4, 64);

    if (c == 0 && cnt < MAX_PER_IMG) { // exactly 100 winners grid-wide
        float vmax = __uint_as_float(~(unsigned int)(ki >> 32));
        int arg = s_arg[ri];
        bool valid = vmax > SCORE_THRESH_F;
        float4 bx = transform_box(rois, deltas, ri, arg);
        out[cnt * 5 + 0] = valid ? vmax : 0.0f;
        out[cnt * 5 + 1] = valid ? bx.x : 0.0f;
        out[cnt * 5 + 2] = valid ? bx.y : 0.0f;
        out[cnt * 5 + 3] = valid ? bx.z : 0.0f;
        out[cnt * 5 + 4] = valid ? bx.w : 0.0f;
        out[500 + cnt] = (float)arg;   // labels_all
        out[600 + cnt] = (float)ri;    // top
    }
}

// ---------------------------------------------------------------------------
extern "C" void kernel_launch(void* const* d_in, const int* in_sizes, int n_in,
                              void* d_out, int out_size, void* d_ws, size_t ws_size,
                              hipStream_t stream) {
    const float* rois   = (const float*)d_in[0];   // [512,4]
    const float* deltas = (const float*)d_in[1];   // [512,324]
    const float* scores = (const float*)d_in[2];   // [512,81]
    float* out = (float*)d_out;                    // 700 floats

    char* ws = (char*)d_ws;                        // ~3.82 MB used
    float4* sbox_g  = (float4*)(ws + 0);                              // 663,552 B
    int*    order_g = (int*)   (ws + 663552);                         // 165,888 B
    float*  ssc_g   = (float*) (ws + 829440);                         // 165,888 B
    int*    valid_g = (int*)   (ws + 995328);                         //     512 B
    float*  dists_t = (float*) (ws + 995840);                         // 165,888 B
    unsigned long long* supT_g = (unsigned long long*)(ws + 1161728); // 2,654,208 B
    int*    done_k  = (int*)   (ws + 3815936);                        //     324 B

    rank_boxes_kernel<<<K, 512, 0, stream>>>(rois, deltas, scores,
                                             sbox_g, order_g, ssc_g,
                                             valid_g, done_k);
    bitmega_kernel   <<<K * 8, 256, 0, stream>>>(sbox_g, valid_g, supT_g,
                                                 order_g, ssc_g, done_k, dists_t);
    finalize_kernel  <<<8, 512, 0, stream>>>(dists_t, rois, deltas, out);
}